// Round 6
// baseline (71.111 us; speedup 1.0000x reference)
//
#include <hip/hip_runtime.h>
#include <math.h>

// Problem constants (fixed by the reference setup)
constexpr int N = 4096;
constexpr int E = 128;
constexpr int H = 8;
constexpr int D = 16;      // E / H
constexpr int SPAN = 50;

// 16 FMAs: acc[c] += sum_j x[j] * wj[c]
__device__ __forceinline__ void fma4x4(const float4 x, const float4 w0,
                                       const float4 w1, const float4 w2,
                                       const float4 w3, float4& a)
{
    a.x = fmaf(x.x, w0.x, a.x); a.y = fmaf(x.x, w0.y, a.y);
    a.z = fmaf(x.x, w0.z, a.z); a.w = fmaf(x.x, w0.w, a.w);
    a.x = fmaf(x.y, w1.x, a.x); a.y = fmaf(x.y, w1.y, a.y);
    a.z = fmaf(x.y, w1.z, a.z); a.w = fmaf(x.y, w1.w, a.w);
    a.x = fmaf(x.z, w2.x, a.x); a.y = fmaf(x.z, w2.y, a.y);
    a.z = fmaf(x.z, w2.z, a.z); a.w = fmaf(x.z, w2.w, a.w);
    a.x = fmaf(x.w, w3.x, a.x); a.y = fmaf(x.w, w3.y, a.y);
    a.z = fmaf(x.w, w3.z, a.z); a.w = fmaf(x.w, w3.w, a.w);
}

// ---------------------------------------------------------------------------
// Kernel 1: fused projections. 512 blocks x 256 threads, 8-row tile.
// Thread = (c4 = tid&31 -> 4 output cols, row = tid>>5 -> 1 row).
// Per 4-k group: 4 coalesced float4 W loads + 1 ds_read_b128 + 16 FMA.
// ---------------------------------------------------------------------------
__global__ __launch_bounds__(256, 2) void proj_kernel(
    const float* __restrict__ query, const float* __restrict__ key,
    const float* __restrict__ value, const float* __restrict__ attn_bias,
    const float* __restrict__ Wq, const float* __restrict__ bq,
    const float* __restrict__ Wk, const float* __restrict__ bk,
    const float* __restrict__ Wv, const float* __restrict__ bv,
    const float* __restrict__ Wfe, const float* __restrict__ bfe,
    float* __restrict__ qo, float* __restrict__ ko,
    float* __restrict__ vo, float* __restrict__ bo_)
{
    __shared__ __align__(16) float xs[3 * 8 * 128 + 64];  // x tiles + ab
    float* ab = xs + 3072;                                // ab[r*8+h]

    const int tid  = threadIdx.x;
    const int c4   = tid & 31;
    const int row  = tid >> 5;        // 0..7
    const int row0 = blockIdx.x * 8;

    // ---- stage X tiles (one float4 per thread per matrix) + attn_bias ----
    {
        const int r = tid >> 5, q = tid & 31;
        *(float4*)&xs[(0 * 8 + r) * 128 + q * 4] =
            ((const float4*)(query + (size_t)(row0 + r) * E))[q];
        *(float4*)&xs[(1 * 8 + r) * 128 + q * 4] =
            ((const float4*)(key + (size_t)(row0 + r) * E))[q];
        *(float4*)&xs[(2 * 8 + r) * 128 + q * 4] =
            ((const float4*)(value + (size_t)(row0 + r) * E))[q];
    }
    if (tid < 64) ab[tid] = attn_bias[(size_t)row0 * H + tid];
    __syncthreads();

    const size_t ro = (size_t)(row0 + row) * E + c4 * 4;

    // ---- q projection ----
    {
        float4 acc = ((const float4*)bq)[c4];
        #pragma unroll 2
        for (int kk = 0; kk < E; kk += 4) {
            const float4 w0 = ((const float4*)(Wq + (size_t)(kk + 0) * E))[c4];
            const float4 w1 = ((const float4*)(Wq + (size_t)(kk + 1) * E))[c4];
            const float4 w2 = ((const float4*)(Wq + (size_t)(kk + 2) * E))[c4];
            const float4 w3 = ((const float4*)(Wq + (size_t)(kk + 3) * E))[c4];
            const float4 x  = *(const float4*)&xs[(0 * 8 + row) * 128 + kk];
            fma4x4(x, w0, w1, w2, w3, acc);
        }
        *(float4*)(qo + ro) = acc;
    }
    // ---- k projection ----
    {
        float4 acc = ((const float4*)bk)[c4];
        #pragma unroll 2
        for (int kk = 0; kk < E; kk += 4) {
            const float4 w0 = ((const float4*)(Wk + (size_t)(kk + 0) * E))[c4];
            const float4 w1 = ((const float4*)(Wk + (size_t)(kk + 1) * E))[c4];
            const float4 w2 = ((const float4*)(Wk + (size_t)(kk + 2) * E))[c4];
            const float4 w3 = ((const float4*)(Wk + (size_t)(kk + 3) * E))[c4];
            const float4 x  = *(const float4*)&xs[(1 * 8 + row) * 128 + kk];
            fma4x4(x, w0, w1, w2, w3, acc);
        }
        *(float4*)(ko + ro) = acc;
    }
    // ---- v projection ----
    {
        float4 acc = ((const float4*)bv)[c4];
        #pragma unroll 2
        for (int kk = 0; kk < E; kk += 4) {
            const float4 w0 = ((const float4*)(Wv + (size_t)(kk + 0) * E))[c4];
            const float4 w1 = ((const float4*)(Wv + (size_t)(kk + 1) * E))[c4];
            const float4 w2 = ((const float4*)(Wv + (size_t)(kk + 2) * E))[c4];
            const float4 w3 = ((const float4*)(Wv + (size_t)(kk + 3) * E))[c4];
            const float4 x  = *(const float4*)&xs[(2 * 8 + row) * 128 + kk];
            fma4x4(x, w0, w1, w2, w3, acc);
        }
        *(float4*)(vo + ro) = acc;
    }
    // ---- feature projection (K = 8) ----
    {
        float4 acc = ((const float4*)bfe)[c4];
        const float4 x0 = *(const float4*)&ab[row * 8];
        const float4 x1 = *(const float4*)&ab[row * 8 + 4];
        const float4 w0 = ((const float4*)(Wfe + 0 * E))[c4];
        const float4 w1 = ((const float4*)(Wfe + 1 * E))[c4];
        const float4 w2 = ((const float4*)(Wfe + 2 * E))[c4];
        const float4 w3 = ((const float4*)(Wfe + 3 * E))[c4];
        fma4x4(x0, w0, w1, w2, w3, acc);
        const float4 w4 = ((const float4*)(Wfe + 4 * E))[c4];
        const float4 w5 = ((const float4*)(Wfe + 5 * E))[c4];
        const float4 w6 = ((const float4*)(Wfe + 6 * E))[c4];
        const float4 w7 = ((const float4*)(Wfe + 7 * E))[c4];
        fma4x4(x1, w4, w5, w6, w7, acc);
        *(float4*)(bo_ + ro) = acc;
    }
}

// ---------------------------------------------------------------------------
// Kernel 2: fused banded attention + output projection.
// 256 blocks x 512 threads (8 waves); block owns 16 rows, wave = head.
// LDS (dynamic, 133120 B):
//   vt [128][132]       : V rows [i0-50, i0+78), shared by ALL heads
//   ew [8][16][112]     : per-(head,row) exp weights, pad-zeroed
//   at [16][128]        : attention output tile (input to the out-GEMM)
// Attention phase is barrier-free per wave; 2 __syncthreads total.
// ---------------------------------------------------------------------------
__global__ __launch_bounds__(512, 2) void attn_out_kernel(
    const float* __restrict__ qw, const float* __restrict__ kw,
    const float* __restrict__ vw, const float* __restrict__ bw,
    const float* __restrict__ Wo, const float* __restrict__ bop,
    float* __restrict__ out)
{
    extern __shared__ __align__(16) float smem[];
    float* vt  = smem;            // 16896 floats
    float* ewb = smem + 16896;    // 14336 floats
    float* at  = smem + 31232;    // 2048 floats

    const int tid  = threadIdx.x;
    const int lane = tid & 63;
    const int h    = __builtin_amdgcn_readfirstlane(tid >> 6);  // head
    const int i0   = blockIdx.x * 16;
    const int base = i0 - SPAN;

    // ---- zero ew (pad slots 101..111 must be 0; rest overwritten) ----
    #pragma unroll
    for (int z = 0; z < 7; ++z)
        ((float4*)ewb)[tid + 512 * z] = make_float4(0.f, 0.f, 0.f, 0.f);

    // ---- stage V rows [base, base+128) once, shared across heads ----
    {
        const int r2 = tid >> 2;          // 0..127
        int j = base + r2;
        j = j < 0 ? 0 : (j > N - 1 ? N - 1 : j);
        const float4* vp = (const float4*)(vw + (size_t)j * E);
        #pragma unroll
        for (int jj = 0; jj < 8; ++jj) {
            const int q = (tid & 3) + jj * 4;   // 0..31
            *(float4*)&vt[r2 * 132 + q * 4] = vp[q];
        }
    }

    // ---- K/B(feature) rows for this lane's two positions -> registers ----
    const int p0 = base + lane;
    const int p1 = p0 + 64;
    const bool in0 = (p0 >= 0);           // p0 <= i0+13 < N always
    const bool in1 = (p1 < N);            // p1 >= 14 always
    const int c0 = p0 < 0 ? 0 : p0;
    const int c1 = p1 > N - 1 ? N - 1 : p1;

    float k0[16], k1[16], g0[16], g1[16];
    {
        const float4* kp0 = (const float4*)(kw + (size_t)c0 * E + h * D);
        const float4* kp1 = (const float4*)(kw + (size_t)c1 * E + h * D);
        const float4* gp0 = (const float4*)(bw + (size_t)c0 * E + h * D);
        const float4* gp1 = (const float4*)(bw + (size_t)c1 * E + h * D);
        #pragma unroll
        for (int x = 0; x < 4; ++x) {
            float4 t;
            t = kp0[x]; k0[4*x]=t.x; k0[4*x+1]=t.y; k0[4*x+2]=t.z; k0[4*x+3]=t.w;
            t = kp1[x]; k1[4*x]=t.x; k1[4*x+1]=t.y; k1[4*x+2]=t.z; k1[4*x+3]=t.w;
            t = gp0[x]; g0[4*x]=t.x; g0[4*x+1]=t.y; g0[4*x+2]=t.z; g0[4*x+3]=t.w;
            t = gp1[x]; g1[4*x]=t.x; g1[4*x+1]=t.y; g1[4*x+2]=t.z; g1[4*x+3]=t.w;
        }
    }
    __syncthreads();

    const float scale = 1.0f / 64.0f;     // 1/sqrt(4096)

    // ---- scores + exp for all 16 rows (per-wave state only) ----
    #pragma unroll 2
    for (int r = 0; r < 16; ++r) {
        // wave-uniform addresses -> scalar loads
        const float* qp = qw + (size_t)(i0 + r) * E + h * D;
        const float* bp = bw + (size_t)(i0 + r) * E + h * D;

        float sq0 = 0.f, sq1 = 0.f, sb0 = 0.f, sb1 = 0.f;
        #pragma unroll
        for (int x = 0; x < 16; ++x) {
            const float qv = qp[x];
            const float bv = bp[x];
            sq0 = fmaf(qv, k0[x], sq0);
            sq1 = fmaf(qv, k1[x], sq1);
            sb0 = fmaf(bv, g0[x], sb0);
            sb1 = fmaf(bv, g1[x], sb1);
        }
        // window membership: w0 = lane-r, w1 = 64+lane-r <= 100
        const bool ok0 = in0 && (lane >= r);
        const bool ok1 = in1 && (lane <= r + 36);
        // no max-subtraction: scores are O(10), exp safe in fp32, softmax
        // without the shift is mathematically identical (validated R3/R4).
        const float e0 = ok0 ? __expf(sq0 * scale + sb0) : 0.f;
        const float e1 = ok1 ? __expf(sq1 * scale + sb1) : 0.f;

        float* ew = ewb + (h * 16 + r) * 112;
        if (lane >= r)      ew[lane - r]      = e0;
        if (lane <= r + 36) ew[64 + lane - r] = e1;
    }

    // ---- PV for all 16 rows; prob-sum folded into the butterfly ----
    {
        const int dq = lane & 3;     // float4 quad of head dim
        const int g  = lane >> 2;    // window group (16)
        #pragma unroll 2
        for (int r = 0; r < 16; ++r) {
            const float* ew = ewb + (h * 16 + r) * 112;
            float ax = 0.f, ay = 0.f, az = 0.f, aw = 0.f, as = 0.f;
            #pragma unroll
            for (int it = 0; it < 7; ++it) {
                const int w = it * 16 + g;           // <= 111, pad is zero
                const float p = ew[w];
                const float4 vv =
                    *(const float4*)&vt[(w + r) * 132 + h * D + dq * 4];
                ax = fmaf(p, vv.x, ax); ay = fmaf(p, vv.y, ay);
                az = fmaf(p, vv.z, az); aw = fmaf(p, vv.w, aw);
                as += p;
            }
            #pragma unroll
            for (int off = 4; off <= 32; off <<= 1) {
                ax += __shfl_xor(ax, off);
                ay += __shfl_xor(ay, off);
                az += __shfl_xor(az, off);
                aw += __shfl_xor(aw, off);
                as += __shfl_xor(as, off);
            }
            if (g == 0) {
                const float inv = 1.0f / as;
                *(float4*)&at[r * 128 + h * D + dq * 4] =
                    make_float4(ax * inv, ay * inv, az * inv, aw * inv);
            }
        }
    }
    __syncthreads();

    // ---- out-projection: out[i0..i0+16) = at @ Wo + bo ----
    {
        const int c4  = tid & 31;
        const int row = tid >> 5;    // 0..15
        float4 acc = ((const float4*)bop)[c4];
        #pragma unroll 2
        for (int kk = 0; kk < E; kk += 4) {
            const float4 w0 = ((const float4*)(Wo + (size_t)(kk + 0) * E))[c4];
            const float4 w1 = ((const float4*)(Wo + (size_t)(kk + 1) * E))[c4];
            const float4 w2 = ((const float4*)(Wo + (size_t)(kk + 2) * E))[c4];
            const float4 w3 = ((const float4*)(Wo + (size_t)(kk + 3) * E))[c4];
            const float4 x  = *(const float4*)&at[row * 128 + kk];
            fma4x4(x, w0, w1, w2, w3, acc);
        }
        *(float4*)(out + (size_t)(i0 + row) * E + c4 * 4) = acc;
    }
}

// ---------------------------------------------------------------------------
extern "C" void kernel_launch(void* const* d_in, const int* in_sizes, int n_in,
                              void* d_out, int out_size, void* d_ws, size_t ws_size,
                              hipStream_t stream) {
    const float* query     = (const float*)d_in[0];
    const float* key       = (const float*)d_in[1];
    const float* value     = (const float*)d_in[2];
    const float* attn_bias = (const float*)d_in[3];
    const float* Wq  = (const float*)d_in[4];
    const float* bq  = (const float*)d_in[5];
    const float* Wk  = (const float*)d_in[6];
    const float* bk  = (const float*)d_in[7];
    const float* Wv  = (const float*)d_in[8];
    const float* bv  = (const float*)d_in[9];
    const float* Wo  = (const float*)d_in[10];
    const float* bo  = (const float*)d_in[11];
    const float* Wfe = (const float*)d_in[12];
    const float* bfe = (const float*)d_in[13];

    float* ws = (float*)d_ws;
    const int NE = N * E;
    float* qw = ws;
    float* kw = ws + 1 * NE;
    float* vw = ws + 2 * NE;
    float* bw = ws + 3 * NE;

    proj_kernel<<<N / 8, 256, 0, stream>>>(query, key, value, attn_bias,
                                           Wq, bq, Wk, bk, Wv, bv, Wfe, bfe,
                                           qw, kw, vw, bw);
    attn_out_kernel<<<N / 16, 512, 33280 * sizeof(float), stream>>>(
        qw, kw, vw, bw, Wo, bo, (float*)d_out);
}